// Round 1
// 298.419 us; speedup vs baseline: 1.0307x; 1.0307x over previous
//
#include <hip/hip_runtime.h>
#include <hip/hip_bf16.h>
#include <stdint.h>

// MultiHeadAttention fused pipeline for MI355X (gfx950).
// B=4, S=2048, E=768, H=12, D=64.
//  prep_transpose: W fp32 -> Wt bf16 (Wt[n][k] = W[k][n])
//  qkv_gemm (z): C[m=e][n=s] = Wt (glds) x X^T (fp32 inline-converted).
//     Epilogue: z=0 Qh plain [BH][S][64]; z=1 Kh d-block XOR-swizzled by s&7;
//     z=2 Vt [BH][64][S], key-block XOR-swizzled by d&7 per 64-key window.
//  attn: double-buffered K/V LDS tiles, ONE barrier per 64-key tile (glds
//     prefetch of tile i+1 overlaps compute of tile i), S^T = K Q^T,
//     fixed-ref softmax via raw v_exp_f32, mask from global int4.
//  out_gemm: C[m=e][n=s] = Wto x ctx^T, float4 stores.
//
// R1: XCD-aware bijective block swizzle (T1) on qkv/attn/out grids.
//   MI355X has 8 XCDs with private L2s; default dispatch round-robins
//   consecutive block ids across XCDs, so blocks sharing an operand panel
//   (6 m-tiles per X-panel in qkv; 16 q-blocks per K/V panel in attn)
//   land on different L2s -> measured 3x (qkv) / 2.8x (attn) L2-miss
//   over-fetch. Remap (gid%8)*cpx + gid/8 (bijective, all grids %8==0)
//   gives each XCD contiguous logical chunks: X panels fetched once,
//   K/V panels L2-resident (6 x 512KB = 3MB < 4MB L2 per XCD).

typedef __bf16 bf16x8 __attribute__((ext_vector_type(8)));
typedef __bf16 bf16x4 __attribute__((ext_vector_type(4)));
typedef float floatx4 __attribute__((ext_vector_type(4)));

#define MFMA_BF16(a, b, c) __builtin_amdgcn_mfma_f32_16x16x32_bf16(a, b, c, 0, 0, 0)

// MFMA 16x16x32 layouts (verified, learn_hip m89/m91):
//   A frag: A[m = lane&15][k = (lane>>4)*8 + j]
//   B frag: B[k = (lane>>4)*8 + j][n = lane&15]   (read from [n][k] storage)
//   C/D  : C[m = (lane>>4)*4 + r][n = lane&15]
// glds16: 64 lanes x 16 B = 1024 B per instruction, dest = uniform base +
// lane*16B. 128B rows -> 8 rows/chunk (lane>>3, (lane&7)*8); 64B rows ->
// 16 rows/chunk (lane>>2, (lane&3)*8).

__device__ __forceinline__ void glds16(const __bf16* g, __bf16* l) {
  __builtin_amdgcn_global_load_lds(
      (const __attribute__((address_space(1))) unsigned int*)g,
      (__attribute__((address_space(3))) unsigned int*)l, 16, 0, 0);
}

// ---------------------------------------------------------------------------
// prep: transpose+convert weights. grid (24, 24, 4), block 256.
// ---------------------------------------------------------------------------
__global__ __launch_bounds__(256) void prep_transpose(
    const float* __restrict__ W0, const float* __restrict__ W1,
    const float* __restrict__ W2, const float* __restrict__ W3,
    __bf16* __restrict__ T0, __bf16* __restrict__ T1,
    __bf16* __restrict__ T2, __bf16* __restrict__ T3) {
  const int z = blockIdx.z;
  const float* W = (z == 0) ? W0 : (z == 1) ? W1 : (z == 2) ? W2 : W3;
  __bf16* T = (z == 0) ? T0 : (z == 1) ? T1 : (z == 2) ? T2 : T3;
  __shared__ float t[32][33];
  const int tx = threadIdx.x & 31, ty = threadIdx.x >> 5;
  const int kb = blockIdx.x * 32, nb = blockIdx.y * 32;
#pragma unroll
  for (int j = 0; j < 4; ++j)
    t[ty + j * 8][tx] = W[(size_t)(kb + ty + j * 8) * 768 + nb + tx];
  __syncthreads();
#pragma unroll
  for (int j = 0; j < 4; ++j)
    T[(size_t)(nb + ty + j * 8) * 768 + kb + tx] = (__bf16)t[tx][ty + j * 8];
}

// ---------------------------------------------------------------------------
// QKV projection GEMM. grid (6, 64, 3), block 256.
// A = Wt (bf16, glds16). B = X (fp32 row-major [8192][768]) staged with
// inline fp32->bf16 convert. C[m=e][n=s]. Tile 128x128, BK=32.
// XCD swizzle: nwg=1152, cpx=144; each XCD gets contiguous logical chunk
// (complete 6-block y-groups sharing one 393KB X panel).
// ---------------------------------------------------------------------------
__global__ __launch_bounds__(256) void qkv_gemm(
    const __bf16* __restrict__ Wtq, const __bf16* __restrict__ Wtk,
    const __bf16* __restrict__ Wtv, const float* __restrict__ Xq,
    const float* __restrict__ Xk, const float* __restrict__ Xv,
    const float* __restrict__ bq, const float* __restrict__ bk,
    const float* __restrict__ bv, __bf16* __restrict__ Qh,
    __bf16* __restrict__ Kh, __bf16* __restrict__ Vt) {
  __shared__ __align__(16) __bf16 As[128 * 32];
  __shared__ __align__(16) __bf16 Bs[128 * 32];
  // ---- XCD-aware bijective swizzle (1152 blocks = 8 XCD x 144)
  const int gid = blockIdx.x + 6 * blockIdx.y + 384 * blockIdx.z;
  const int swz = (gid & 7) * 144 + (gid >> 3);
  const int z = swz / 384;
  const int rem = swz - z * 384;
  const int by = rem / 6;
  const int bx = rem - by * 6;

  const __bf16* Aop = (z == 0) ? Wtq : (z == 1) ? Wtk : Wtv;
  const float* Bop = (z == 0) ? Xq : (z == 1) ? Xk : Xv;
  const float* bias = (z == 0) ? bq : (z == 1) ? bk : bv;
  __bf16* Dst = (z == 0) ? Qh : (z == 1) ? Kh : Vt;
  const int m0 = bx * 128, n0 = by * 128;

  const int tid = threadIdx.x, lane = tid & 63, w = tid >> 6;
  const int quad = lane >> 4, l16 = lane & 15;
  const int wm = (w >> 1) * 64, wn = (w & 1) * 64;

  // A staging (glds, 64 B rows): wave w insts j=0,1 -> rows w*32+j*16+(lane>>2)
  const int garow = w * 32 + (lane >> 2);
  const int gacol = (lane & 3) * 8;
  const __bf16* gA = Aop + (size_t)(m0 + garow) * 768 + gacol;
  __bf16* lA = As + w * 1024;  // chunks of 512 elems per inst
  // B staging (explicit fp32): pass j covers rows (tid>>3)+32j, col (tid&7)*4
  const int brow = tid >> 3, bcol = (tid & 7) * 4;

  floatx4 acc[4][4] = {};

  for (int k0 = 0; k0 < 768; k0 += 32) {
    __syncthreads();
    glds16(gA, lA);
    glds16(gA + (size_t)16 * 768, lA + 512);
    gA += 32;
    float4 f[4];
#pragma unroll
    for (int j = 0; j < 4; ++j)
      f[j] = *(const float4*)&Bop[(size_t)(n0 + brow + 32 * j) * 768 + k0 + bcol];
#pragma unroll
    for (int j = 0; j < 4; ++j) {
      bf16x4 pv;
      pv[0] = (__bf16)f[j].x; pv[1] = (__bf16)f[j].y;
      pv[2] = (__bf16)f[j].z; pv[3] = (__bf16)f[j].w;
      *(bf16x4*)&Bs[(brow + 32 * j) * 32 + bcol] = pv;
    }
    __syncthreads();
    bf16x8 af[4], bfr[4];
#pragma unroll
    for (int t = 0; t < 4; ++t) {
      af[t] = *(const bf16x8*)&As[(wm + t * 16 + l16) * 32 + quad * 8];
      bfr[t] = *(const bf16x8*)&Bs[(wn + t * 16 + l16) * 32 + quad * 8];
    }
#pragma unroll
    for (int mt = 0; mt < 4; ++mt)
#pragma unroll
      for (int nt = 0; nt < 4; ++nt)
        acc[mt][nt] = MFMA_BF16(af[mt], bfr[nt], acc[mt][nt]);
  }

  // epilogue
#pragma unroll
  for (int mt = 0; mt < 4; ++mt) {
    const int e = m0 + wm + mt * 16 + quad * 4;
    const float4 b4 = *(const float4*)&bias[e];
    const int h = e >> 6, d = e & 63;
#pragma unroll
    for (int nt = 0; nt < 4; ++nt) {
      const int s = n0 + wn + nt * 16 + l16;
      const int bb = s >> 11, sr = s & 2047;
      const float v0 = acc[mt][nt][0] + b4.x;
      const float v1 = acc[mt][nt][1] + b4.y;
      const float v2 = acc[mt][nt][2] + b4.z;
      const float v3 = acc[mt][nt][3] + b4.w;
      if (z < 2) {
        bf16x4 pv;
        pv[0] = (__bf16)v0; pv[1] = (__bf16)v1; pv[2] = (__bf16)v2; pv[3] = (__bf16)v3;
        // z==1 (K): swizzle d-block by s&7 so attn LDS reads are conflict-free
        const int col = (z == 0) ? d : ((((d >> 3) ^ (sr & 7)) << 3) | (d & 7));
        *(bf16x4*)&Dst[((size_t)(bb * 12 + h) * 2048 + sr) * 64 + col] = pv;
      } else {
        // V^T: swizzle key-block within each 64-key window by (d+r)&7
        const size_t rowbase = ((size_t)(bb * 12 + h) * 64 + d) * 2048;
        const int shi = sr & ~63, sblk = (sr >> 3) & 7, soff = sr & 7;
        Dst[rowbase + 0 * 2048 + shi + (((sblk ^ ((d + 0) & 7))) << 3) + soff] = (__bf16)v0;
        Dst[rowbase + 1 * 2048 + shi + (((sblk ^ ((d + 1) & 7))) << 3) + soff] = (__bf16)v1;
        Dst[rowbase + 2 * 2048 + shi + (((sblk ^ ((d + 2) & 7))) << 3) + soff] = (__bf16)v2;
        Dst[rowbase + 3 * 2048 + shi + (((sblk ^ ((d + 3) & 7))) << 3) + soff] = (__bf16)v3;
      }
    }
  }
}

// ---------------------------------------------------------------------------
// Output projection GEMM. grid (6, 64), block 256. Both operands bf16, glds.
// XCD swizzle: nwg=384, cpx=48 (8 complete y-groups + whole Wto per XCD).
// ---------------------------------------------------------------------------
__global__ __launch_bounds__(256) void out_gemm(const __bf16* __restrict__ Wto,
                                                const __bf16* __restrict__ Ctx,
                                                const float* __restrict__ bo,
                                                float* __restrict__ Out) {
  __shared__ __align__(16) __bf16 As[128 * 32];
  __shared__ __align__(16) __bf16 Bs[128 * 32];
  const int gid = blockIdx.x + 6 * blockIdx.y;
  const int swz = (gid & 7) * 48 + (gid >> 3);
  const int by = swz / 6;
  const int bx = swz - by * 6;
  const int m0 = bx * 128, n0 = by * 128;
  const int tid = threadIdx.x, lane = tid & 63, w = tid >> 6;
  const int quad = lane >> 4, l16 = lane & 15;
  const int wm = (w >> 1) * 64, wn = (w & 1) * 64;

  const int grow = w * 32 + (lane >> 2);
  const int gcol = (lane & 3) * 8;
  const __bf16* gA = Wto + (size_t)(m0 + grow) * 768 + gcol;
  const __bf16* gB = Ctx + (size_t)(n0 + grow) * 768 + gcol;
  __bf16* lA = As + w * 1024;
  __bf16* lB = Bs + w * 1024;

  floatx4 acc[4][4] = {};
  for (int k0 = 0; k0 < 768; k0 += 32) {
    __syncthreads();
    glds16(gA, lA);
    glds16(gA + (size_t)16 * 768, lA + 512);
    glds16(gB, lB);
    glds16(gB + (size_t)16 * 768, lB + 512);
    gA += 32;
    gB += 32;
    __syncthreads();
    bf16x8 af[4], bfr[4];
#pragma unroll
    for (int t = 0; t < 4; ++t) {
      af[t] = *(const bf16x8*)&As[(wm + t * 16 + l16) * 32 + quad * 8];
      bfr[t] = *(const bf16x8*)&Bs[(wn + t * 16 + l16) * 32 + quad * 8];
    }
#pragma unroll
    for (int mt = 0; mt < 4; ++mt)
#pragma unroll
      for (int nt = 0; nt < 4; ++nt)
        acc[mt][nt] = MFMA_BF16(af[mt], bfr[nt], acc[mt][nt]);
  }

#pragma unroll
  for (int mt = 0; mt < 4; ++mt) {
    const int e = m0 + wm + mt * 16 + quad * 4;
    const float4 b4 = *(const float4*)&bo[e];
#pragma unroll
    for (int nt = 0; nt < 4; ++nt) {
      const int s = n0 + wn + nt * 16 + l16;
      float4 r;
      r.x = acc[mt][nt][0] + b4.x;
      r.y = acc[mt][nt][1] + b4.y;
      r.z = acc[mt][nt][2] + b4.z;
      r.w = acc[mt][nt][3] + b4.w;
      *(float4*)&Out[(size_t)s * 768 + e] = r;
    }
  }
}

// ---------------------------------------------------------------------------
// Flash attention, double-buffered shared-LDS K/V tiles, ONE barrier/iter.
// grid (16, 48), block 256 (4 waves). Iter i: barrier (tile-i staging from
// iter i-1 drains here, after a full compute phase in flight); issue glds
// prefetch of tile i+1 into the other buffer; compute tile i. The prefetch
// buffer was last read in iter i-1 (finished before this barrier) -> safe.
// Swizzled K/V layouts (block ^= row&7) keep LDS frag reads ~conflict-free.
// S^T = K Q^T; softmax via raw v_exp_f32 (scores O(10), no denormal risk);
// mask int4 from global (L1-resident). P^T via per-wave LDS (no barrier).
// XCD swizzle: nwg=768, cpx=96; each XCD owns 6 complete (b,h) groups ->
// its 16 q-blocks/panel + 512KB K/V panel stay in the XCD's L2 (3MB/4MB).
// ---------------------------------------------------------------------------
__global__ __launch_bounds__(256) void attn_kernel(
    const __bf16* __restrict__ Qh, const __bf16* __restrict__ Kh,
    const __bf16* __restrict__ Vt, const int* __restrict__ mask,
    __bf16* __restrict__ ctx) {
  const int lid = blockIdx.x + 16 * blockIdx.y;
  const int swz = (lid & 7) * 96 + (lid >> 3);
  const int qx = swz & 15, bh = swz >> 4;
  const int b = bh / 12, h = bh - b * 12;
  const int tid = threadIdx.x, lane = tid & 63, w = tid >> 6;
  const int quad = lane >> 4, l16 = lane & 15;
  const int q0 = qx * 128 + w * 32;

  __shared__ __align__(16) __bf16 Ks[2][64 * 64];     // [buf][key][d-swz]
  __shared__ __align__(16) __bf16 Vs[2][64 * 64];     // [buf][d][key-swz]
  __shared__ __align__(16) __bf16 Plds[4][32][72];    // [wave][q][key(+pad)]

  const __bf16* Qbase = Qh + (size_t)bh * 2048 * 64;
  const __bf16* Kbase = Kh + (size_t)bh * 2048 * 64;
  const __bf16* Vbase = Vt + (size_t)bh * 64 * 2048;
  const int* maskB = mask + b * 2048;

  // Q B-frags (plain layout): B[k=d][n=q] from Qh[q][d]
  bf16x8 bqf[2][2];
#pragma unroll
  for (int qt = 0; qt < 2; ++qt)
#pragma unroll
    for (int c = 0; c < 2; ++c)
      bqf[qt][c] =
          *(const bf16x8*)&Qbase[(size_t)(q0 + qt * 16 + l16) * 64 + c * 32 + quad * 8];

  // staging (128 B rows): chunk c covers rows c*8 + (lane>>3), col (lane&7)*8
  const int r0 = (w * 2) * 8 + (lane >> 3);
  const int r1 = (w * 2 + 1) * 8 + (lane >> 3);
  const int scol = (lane & 7) * 8;
  const int d0 = (w * 2) * 512;      // LDS chunk offsets (elems)
  const int d1 = (w * 2 + 1) * 512;
  // swizzled fragment column base: block = quad ^ (l16&7)
  const int col0 = (quad ^ (l16 & 7)) * 8;

  // prologue: stage tile 0 into buffer 0
  glds16(&Kbase[(size_t)r0 * 64 + scol], &Ks[0][d0]);
  glds16(&Kbase[(size_t)r1 * 64 + scol], &Ks[0][d1]);
  glds16(&Vbase[(size_t)r0 * 2048 + scol], &Vs[0][d0]);
  glds16(&Vbase[(size_t)r1 * 2048 + scol], &Vs[0][d1]);

  floatx4 o[4][2] = {};  // O^T accs: [d-tile][q-tile]
  float rS[2] = {0.0f, 0.0f};
  const float SC = 0.18033688011112042f;  // 0.125 * log2(e)

  for (int it = 0; it < 32; ++it) {
    const int kt = it * 64;
    const int cur = it & 1;
    const int nxt = cur ^ 1;
    const int nkt = (kt + 64) & 2047;  // wrap: last-iter prefetch is harmless

    __syncthreads();  // drains tile-`it` staging (in flight since iter it-1)

    // ---- prefetch tile it+1 into the other buffer (overlaps compute below)
    glds16(&Kbase[(size_t)(nkt + r0) * 64 + scol], &Ks[nxt][d0]);
    glds16(&Kbase[(size_t)(nkt + r1) * 64 + scol], &Ks[nxt][d1]);
    glds16(&Vbase[(size_t)r0 * 2048 + nkt + scol], &Vs[nxt][d0]);
    glds16(&Vbase[(size_t)r1 * 2048 + nkt + scol], &Vs[nxt][d1]);

    // ---- mask bias for this tile (L1-resident int4 loads)
    int4 mk[4];
#pragma unroll
    for (int t = 0; t < 4; ++t) mk[t] = *(const int4*)&maskB[kt + t * 16 + quad * 4];

    // ---- scores S^T: 4 key-tiles x 2 q-tiles
    floatx4 sc[4][2];
#pragma unroll
    for (int t = 0; t < 4; ++t) {
      bf16x8 ak0 = *(const bf16x8*)&Ks[cur][(t * 16 + l16) * 64 + col0];
      bf16x8 ak1 = *(const bf16x8*)&Ks[cur][(t * 16 + l16) * 64 + (col0 ^ 32)];
#pragma unroll
      for (int qt = 0; qt < 2; ++qt) {
        floatx4 zz = {};
        zz = MFMA_BF16(ak0, bqf[qt][0], zz);
        zz = MFMA_BF16(ak1, bqf[qt][1], zz);
        sc[t][qt] = zz;
      }
    }
    // ---- p = exp2(s*SC + bias); per-lane partial sums
#pragma unroll
    for (int t = 0; t < 4; ++t) {
      const float k0f = mk[t].x ? 0.0f : -1e5f;
      const float k1f = mk[t].y ? 0.0f : -1e5f;
      const float k2f = mk[t].z ? 0.0f : -1e5f;
      const float k3f = mk[t].w ? 0.0f : -1e5f;
#pragma unroll
      for (int qt = 0; qt < 2; ++qt) {
        floatx4 p;
        p[0] = __builtin_amdgcn_exp2f(fmaf(sc[t][qt][0], SC, k0f));
        p[1] = __builtin_amdgcn_exp2f(fmaf(sc[t][qt][1], SC, k1f));
        p[2] = __builtin_amdgcn_exp2f(fmaf(sc[t][qt][2], SC, k2f));
        p[3] = __builtin_amdgcn_exp2f(fmaf(sc[t][qt][3], SC, k3f));
        sc[t][qt] = p;
        rS[qt] += p[0] + p[1] + p[2] + p[3];
      }
    }
    // ---- pack P^T into Plds[q][key] (4 consecutive keys/lane -> b64)
#pragma unroll
    for (int qt = 0; qt < 2; ++qt)
#pragma unroll
      for (int t = 0; t < 4; ++t) {
        bf16x4 pv;
        pv[0] = (__bf16)sc[t][qt][0];
        pv[1] = (__bf16)sc[t][qt][1];
        pv[2] = (__bf16)sc[t][qt][2];
        pv[3] = (__bf16)sc[t][qt][3];
        *(bf16x4*)&Plds[w][qt * 16 + l16][t * 16 + quad * 4] = pv;
      }
    // ---- O^T += V^T @ P^T  (per-wave Plds; in-wave lgkmcnt only)
#pragma unroll
    for (int c = 0; c < 2; ++c) {
      bf16x8 bp[2];
#pragma unroll
      for (int qt = 0; qt < 2; ++qt)
        bp[qt] = *(const bf16x8*)&Plds[w][qt * 16 + l16][c * 32 + quad * 8];
#pragma unroll
      for (int dt = 0; dt < 4; ++dt) {
        bf16x8 av = *(const bf16x8*)&Vs[cur][(dt * 16 + l16) * 64 + (col0 ^ (c * 32))];
#pragma unroll
        for (int qt = 0; qt < 2; ++qt) o[dt][qt] = MFMA_BF16(av, bp[qt], o[dt][qt]);
      }
    }
  }

  // ---- cross-lane sum (across quads) + normalize + write ctx
  float inv[2];
#pragma unroll
  for (int qt = 0; qt < 2; ++qt) {
    float s = rS[qt];
    s += __shfl_xor(s, 16, 64);
    s += __shfl_xor(s, 32, 64);
    inv[qt] = 1.0f / s;
  }
#pragma unroll
  for (int dt = 0; dt < 4; ++dt)
#pragma unroll
    for (int qt = 0; qt < 2; ++qt) {
      const int q = q0 + qt * 16 + l16;
      const int d = h * 64 + dt * 16 + quad * 4;
      bf16x4 pv;
      pv[0] = (__bf16)(o[dt][qt][0] * inv[qt]);
      pv[1] = (__bf16)(o[dt][qt][1] * inv[qt]);
      pv[2] = (__bf16)(o[dt][qt][2] * inv[qt]);
      pv[3] = (__bf16)(o[dt][qt][3] * inv[qt]);
      *(bf16x4*)&ctx[(size_t)(b * 2048 + q) * 768 + d] = pv;
    }
}

// ---------------------------------------------------------------------------
extern "C" void kernel_launch(void* const* d_in, const int* in_sizes, int n_in,
                              void* d_out, int out_size, void* d_ws, size_t ws_size,
                              hipStream_t stream) {
  const float* q = (const float*)d_in[0];
  const float* k = (const float*)d_in[1];
  const float* v = (const float*)d_in[2];
  const int* mask = (const int*)d_in[3];
  const float* Wq = (const float*)d_in[4];
  const float* bq = (const float*)d_in[5];
  const float* Wk = (const float*)d_in[6];
  const float* bk = (const float*)d_in[7];
  const float* Wv = (const float*)d_in[8];
  const float* bv = (const float*)d_in[9];
  const float* Wo = (const float*)d_in[10];
  const float* bo = (const float*)d_in[11];
  float* out = (float*)d_out;

  char* ws = (char*)d_ws;
  const size_t SZ = (size_t)8192 * 768 * 2;   // 12.58 MB
  const size_t WSZ = (size_t)768 * 768 * 2;   // 1.18 MB
  __bf16* Qh = (__bf16*)(ws);
  __bf16* Kh = (__bf16*)(ws + SZ);
  __bf16* Vt = (__bf16*)(ws + 2 * SZ);
  __bf16* ctx = (__bf16*)(ws + 3 * SZ);
  __bf16* Wtq = (__bf16*)(ws + 4 * SZ);
  __bf16* Wtk = (__bf16*)(ws + 4 * SZ + WSZ);
  __bf16* Wtv = (__bf16*)(ws + 4 * SZ + 2 * WSZ);
  __bf16* Wto = (__bf16*)(ws + 4 * SZ + 3 * WSZ);

  prep_transpose<<<dim3(24, 24, 4), 256, 0, stream>>>(Wq, Wk, Wv, Wo, Wtq, Wtk, Wtv, Wto);
  qkv_gemm<<<dim3(6, 64, 3), 256, 0, stream>>>(Wtq, Wtk, Wtv, q, k, v, bq, bk, bv,
                                               Qh, Kh, Vt);
  attn_kernel<<<dim3(16, 48), 256, 0, stream>>>(Qh, Kh, Vt, mask, ctx);
  out_gemm<<<dim3(6, 64), 256, 0, stream>>>(Wto, ctx, bo, out);
}

// Round 3
// 280.594 us; speedup vs baseline: 1.0962x; 1.0635x over previous
//
#include <hip/hip_runtime.h>
#include <hip/hip_bf16.h>
#include <stdint.h>

// MultiHeadAttention fused pipeline for MI355X (gfx950).
// B=4, S=2048, E=768, H=12, D=64.
//  prep_transpose: W fp32 -> Wt bf16 (Wt[n][k] = W[k][n]); also mask->biasF.
//  qkv_gemm (z): C[m=e][n=s] = Wt (glds) x X^T (fp32 inline-converted).
//     Epilogue: z=0 Qh plain [BH][S][64] PRE-SCALED by 0.125*log2e;
//     z=1 Kh d-block XOR-swizzled by s&7; z=2 Vt [BH][64][S], key-block
//     XOR-swizzled by d&7 per 64-key window.
//  attn: double-buffered K/V LDS tiles, ONE barrier per 64-key tile,
//     S^T = K Q^T with bias in MFMA acc-init, p=exp2(s) direct,
//     in-register P^T transpose (cvt_pk_bf16 + permlane32/16_swap),
//     rS via ones-row MFMA (no cross-lane reduce).
//  out_gemm: C[m=e][n=s] = Wto x ctx^T, float4 stores.
//
// R1: XCD-aware bijective block swizzle (T1) on qkv/attn/out grids.
//   attn FETCH 107.7->18.5 MB confirmed L2-residency; dur unchanged ->
//   attn is on-chip bound (LDS pipe ~48us + VALU ~45us co-bound).
// R2: attn LDS/VALU diet:
//   - Plds round-trip (4 reads + 8 writes/iter, ALL 4.7M bank conflicts,
//     18KB LDS) replaced by in-register transpose: per (qt,c)
//     2x permlane32_swap + 2x permlane16_swap on cvt_pk'd bf16 words.
//     Mapping (re-verified lane-for-lane): dest lane(qd,l16) word j <-
//     src lane (quad=(2qd+(j>>1))&3, l16), tile t=2c+(qd>>1), pair j&1.
//     permlane32(X,Y): X'={X.r0,X.r1,Y.r0,Y.r1} Y'={X.r2,X.r3,Y.r2,Y.r3};
//     permlane16(X,Y): X'={X.r0,Y.r0,X.r2,Y.r2} Y'={X.r1,Y.r1,X.r3,Y.r3}.
//   - mask bias as f32 table (prep), fed to QK^T MFMA acc-init: kills
//     32 fmaf + 32 cndmask per iter. Q pre-scaled by SC in qkv.
//   - rS via MFMA(ones, bp): denominator from the SAME bf16 P as the
//     numerator; every lane holds its q's sum -> no final shuffles.
// R3: resubmit of R2 (container-level failure, no error text): permlane
//   swaps via __builtin_amdgcn_permlane{32,16}_swap when available
//   (__has_builtin guard), inline-asm fallback otherwise.

typedef __bf16 bf16x8 __attribute__((ext_vector_type(8)));
typedef __bf16 bf16x4 __attribute__((ext_vector_type(4)));
typedef float floatx4 __attribute__((ext_vector_type(4)));

#define MFMA_BF16(a, b, c) __builtin_amdgcn_mfma_f32_16x16x32_bf16(a, b, c, 0, 0, 0)

// MFMA 16x16x32 layouts (verified, learn_hip m89/m91):
//   A frag: A[m = lane&15][k = (lane>>4)*8 + j]
//   B frag: B[k = (lane>>4)*8 + j][n = lane&15]   (read from [n][k] storage)
//   C/D  : C[m = (lane>>4)*4 + r][n = lane&15]

__device__ __forceinline__ void glds16(const __bf16* g, __bf16* l) {
  __builtin_amdgcn_global_load_lds(
      (const __attribute__((address_space(1))) unsigned int*)g,
      (__attribute__((address_space(3))) unsigned int*)l, 16, 0, 0);
}

#if __has_builtin(__builtin_amdgcn_permlane32_swap)
__device__ __forceinline__ void perm32_swap(unsigned int& a, unsigned int& b) {
  auto r = __builtin_amdgcn_permlane32_swap(a, b, false, false);
  a = r[0];
  b = r[1];
}
#else
__device__ __forceinline__ void perm32_swap(unsigned int& a, unsigned int& b) {
  asm("v_permlane32_swap_b32 %0, %1" : "+v"(a), "+v"(b));
}
#endif

#if __has_builtin(__builtin_amdgcn_permlane16_swap)
__device__ __forceinline__ void perm16_swap(unsigned int& a, unsigned int& b) {
  auto r = __builtin_amdgcn_permlane16_swap(a, b, false, false);
  a = r[0];
  b = r[1];
}
#else
__device__ __forceinline__ void perm16_swap(unsigned int& a, unsigned int& b) {
  asm("v_permlane16_swap_b32 %0, %1" : "+v"(a), "+v"(b));
}
#endif

// ---------------------------------------------------------------------------
// prep: transpose+convert weights; 8 of the z==3 blocks also build the
// f32 mask-bias table (mask ? 0 : -1e5). grid (24, 24, 4), block 256.
// ---------------------------------------------------------------------------
__global__ __launch_bounds__(256) void prep_transpose(
    const float* __restrict__ W0, const float* __restrict__ W1,
    const float* __restrict__ W2, const float* __restrict__ W3,
    __bf16* __restrict__ T0, __bf16* __restrict__ T1,
    __bf16* __restrict__ T2, __bf16* __restrict__ T3,
    const int* __restrict__ mask, float* __restrict__ biasF) {
  const int z = blockIdx.z;
  const float* W = (z == 0) ? W0 : (z == 1) ? W1 : (z == 2) ? W2 : W3;
  __bf16* T = (z == 0) ? T0 : (z == 1) ? T1 : (z == 2) ? T2 : T3;
  __shared__ float t[32][33];
  const int tx = threadIdx.x & 31, ty = threadIdx.x >> 5;
  const int kb = blockIdx.x * 32, nb = blockIdx.y * 32;
#pragma unroll
  for (int j = 0; j < 4; ++j)
    t[ty + j * 8][tx] = W[(size_t)(kb + ty + j * 8) * 768 + nb + tx];
  if (z == 3 && blockIdx.y == 0 && blockIdx.x < 8) {
    const int idx = blockIdx.x * 1024 + threadIdx.x * 4;
    const int4 m4 = *(const int4*)&mask[idx];
    float4 f4;
    f4.x = m4.x ? 0.0f : -1e5f;
    f4.y = m4.y ? 0.0f : -1e5f;
    f4.z = m4.z ? 0.0f : -1e5f;
    f4.w = m4.w ? 0.0f : -1e5f;
    *(float4*)&biasF[idx] = f4;
  }
  __syncthreads();
#pragma unroll
  for (int j = 0; j < 4; ++j)
    T[(size_t)(nb + ty + j * 8) * 768 + kb + tx] = (__bf16)t[tx][ty + j * 8];
}

// ---------------------------------------------------------------------------
// QKV projection GEMM. grid (6, 64, 3), block 256.
// XCD swizzle: nwg=1152, cpx=144.
// ---------------------------------------------------------------------------
__global__ __launch_bounds__(256) void qkv_gemm(
    const __bf16* __restrict__ Wtq, const __bf16* __restrict__ Wtk,
    const __bf16* __restrict__ Wtv, const float* __restrict__ Xq,
    const float* __restrict__ Xk, const float* __restrict__ Xv,
    const float* __restrict__ bq, const float* __restrict__ bk,
    const float* __restrict__ bv, __bf16* __restrict__ Qh,
    __bf16* __restrict__ Kh, __bf16* __restrict__ Vt) {
  __shared__ __align__(16) __bf16 As[128 * 32];
  __shared__ __align__(16) __bf16 Bs[128 * 32];
  const int gid = blockIdx.x + 6 * blockIdx.y + 384 * blockIdx.z;
  const int swz = (gid & 7) * 144 + (gid >> 3);
  const int z = swz / 384;
  const int rem = swz - z * 384;
  const int by = rem / 6;
  const int bx = rem - by * 6;

  const __bf16* Aop = (z == 0) ? Wtq : (z == 1) ? Wtk : Wtv;
  const float* Bop = (z == 0) ? Xq : (z == 1) ? Xk : Xv;
  const float* bias = (z == 0) ? bq : (z == 1) ? bk : bv;
  __bf16* Dst = (z == 0) ? Qh : (z == 1) ? Kh : Vt;
  const int m0 = bx * 128, n0 = by * 128;

  const int tid = threadIdx.x, lane = tid & 63, w = tid >> 6;
  const int quad = lane >> 4, l16 = lane & 15;
  const int wm = (w >> 1) * 64, wn = (w & 1) * 64;

  const int garow = w * 32 + (lane >> 2);
  const int gacol = (lane & 3) * 8;
  const __bf16* gA = Aop + (size_t)(m0 + garow) * 768 + gacol;
  __bf16* lA = As + w * 1024;
  const int brow = tid >> 3, bcol = (tid & 7) * 4;

  floatx4 acc[4][4] = {};

  for (int k0 = 0; k0 < 768; k0 += 32) {
    __syncthreads();
    glds16(gA, lA);
    glds16(gA + (size_t)16 * 768, lA + 512);
    gA += 32;
    float4 f[4];
#pragma unroll
    for (int j = 0; j < 4; ++j)
      f[j] = *(const float4*)&Bop[(size_t)(n0 + brow + 32 * j) * 768 + k0 + bcol];
#pragma unroll
    for (int j = 0; j < 4; ++j) {
      bf16x4 pv;
      pv[0] = (__bf16)f[j].x; pv[1] = (__bf16)f[j].y;
      pv[2] = (__bf16)f[j].z; pv[3] = (__bf16)f[j].w;
      *(bf16x4*)&Bs[(brow + 32 * j) * 32 + bcol] = pv;
    }
    __syncthreads();
    bf16x8 af[4], bfr[4];
#pragma unroll
    for (int t = 0; t < 4; ++t) {
      af[t] = *(const bf16x8*)&As[(wm + t * 16 + l16) * 32 + quad * 8];
      bfr[t] = *(const bf16x8*)&Bs[(wn + t * 16 + l16) * 32 + quad * 8];
    }
#pragma unroll
    for (int mt = 0; mt < 4; ++mt)
#pragma unroll
      for (int nt = 0; nt < 4; ++nt)
        acc[mt][nt] = MFMA_BF16(af[mt], bfr[nt], acc[mt][nt]);
  }

  // epilogue; z==0 pre-scales Q by 0.125*log2e (softmax scale fold)
  const float qs = (z == 0) ? 0.18033688011112042f : 1.0f;
#pragma unroll
  for (int mt = 0; mt < 4; ++mt) {
    const int e = m0 + wm + mt * 16 + quad * 4;
    const float4 b4 = *(const float4*)&bias[e];
    const int h = e >> 6, d = e & 63;
#pragma unroll
    for (int nt = 0; nt < 4; ++nt) {
      const int s = n0 + wn + nt * 16 + l16;
      const int bb = s >> 11, sr = s & 2047;
      const float v0 = (acc[mt][nt][0] + b4.x) * qs;
      const float v1 = (acc[mt][nt][1] + b4.y) * qs;
      const float v2 = (acc[mt][nt][2] + b4.z) * qs;
      const float v3 = (acc[mt][nt][3] + b4.w) * qs;
      if (z < 2) {
        bf16x4 pv;
        pv[0] = (__bf16)v0; pv[1] = (__bf16)v1; pv[2] = (__bf16)v2; pv[3] = (__bf16)v3;
        const int col = (z == 0) ? d : ((((d >> 3) ^ (sr & 7)) << 3) | (d & 7));
        *(bf16x4*)&Dst[((size_t)(bb * 12 + h) * 2048 + sr) * 64 + col] = pv;
      } else {
        const size_t rowbase = ((size_t)(bb * 12 + h) * 64 + d) * 2048;
        const int shi = sr & ~63, sblk = (sr >> 3) & 7, soff = sr & 7;
        Dst[rowbase + 0 * 2048 + shi + (((sblk ^ ((d + 0) & 7))) << 3) + soff] = (__bf16)v0;
        Dst[rowbase + 1 * 2048 + shi + (((sblk ^ ((d + 1) & 7))) << 3) + soff] = (__bf16)v1;
        Dst[rowbase + 2 * 2048 + shi + (((sblk ^ ((d + 2) & 7))) << 3) + soff] = (__bf16)v2;
        Dst[rowbase + 3 * 2048 + shi + (((sblk ^ ((d + 3) & 7))) << 3) + soff] = (__bf16)v3;
      }
    }
  }
}

// ---------------------------------------------------------------------------
// Output projection GEMM. grid (6, 64), block 256. XCD swizzle cpx=48.
// ---------------------------------------------------------------------------
__global__ __launch_bounds__(256) void out_gemm(const __bf16* __restrict__ Wto,
                                                const __bf16* __restrict__ Ctx,
                                                const float* __restrict__ bo,
                                                float* __restrict__ Out) {
  __shared__ __align__(16) __bf16 As[128 * 32];
  __shared__ __align__(16) __bf16 Bs[128 * 32];
  const int gid = blockIdx.x + 6 * blockIdx.y;
  const int swz = (gid & 7) * 48 + (gid >> 3);
  const int by = swz / 6;
  const int bx = swz - by * 6;
  const int m0 = bx * 128, n0 = by * 128;
  const int tid = threadIdx.x, lane = tid & 63, w = tid >> 6;
  const int quad = lane >> 4, l16 = lane & 15;
  const int wm = (w >> 1) * 64, wn = (w & 1) * 64;

  const int grow = w * 32 + (lane >> 2);
  const int gcol = (lane & 3) * 8;
  const __bf16* gA = Wto + (size_t)(m0 + grow) * 768 + gcol;
  const __bf16* gB = Ctx + (size_t)(n0 + grow) * 768 + gcol;
  __bf16* lA = As + w * 1024;
  __bf16* lB = Bs + w * 1024;

  floatx4 acc[4][4] = {};
  for (int k0 = 0; k0 < 768; k0 += 32) {
    __syncthreads();
    glds16(gA, lA);
    glds16(gA + (size_t)16 * 768, lA + 512);
    glds16(gB, lB);
    glds16(gB + (size_t)16 * 768, lB + 512);
    gA += 32;
    gB += 32;
    __syncthreads();
    bf16x8 af[4], bfr[4];
#pragma unroll
    for (int t = 0; t < 4; ++t) {
      af[t] = *(const bf16x8*)&As[(wm + t * 16 + l16) * 32 + quad * 8];
      bfr[t] = *(const bf16x8*)&Bs[(wn + t * 16 + l16) * 32 + quad * 8];
    }
#pragma unroll
    for (int mt = 0; mt < 4; ++mt)
#pragma unroll
      for (int nt = 0; nt < 4; ++nt)
        acc[mt][nt] = MFMA_BF16(af[mt], bfr[nt], acc[mt][nt]);
  }

#pragma unroll
  for (int mt = 0; mt < 4; ++mt) {
    const int e = m0 + wm + mt * 16 + quad * 4;
    const float4 b4 = *(const float4*)&bo[e];
#pragma unroll
    for (int nt = 0; nt < 4; ++nt) {
      const int s = n0 + wn + nt * 16 + l16;
      float4 r;
      r.x = acc[mt][nt][0] + b4.x;
      r.y = acc[mt][nt][1] + b4.y;
      r.z = acc[mt][nt][2] + b4.z;
      r.w = acc[mt][nt][3] + b4.w;
      *(float4*)&Out[(size_t)s * 768 + e] = r;
    }
  }
}

// ---------------------------------------------------------------------------
// Flash attention. grid (16, 48), block 256 (4 waves). Double-buffered K/V,
// one barrier/iter; bias in QK^T acc-init; exp2 direct; in-register P^T
// transpose via cvt_pk_bf16 + permlane32/16_swap; rS via ones-row MFMA.
// XCD swizzle: cpx=96; K/V panels L2-resident per XCD.
// ---------------------------------------------------------------------------
__global__ __launch_bounds__(256) void attn_kernel(
    const __bf16* __restrict__ Qh, const __bf16* __restrict__ Kh,
    const __bf16* __restrict__ Vt, const float* __restrict__ biasF,
    __bf16* __restrict__ ctx) {
  const int lid = blockIdx.x + 16 * blockIdx.y;
  const int swz = (lid & 7) * 96 + (lid >> 3);
  const int qx = swz & 15, bh = swz >> 4;
  const int b = bh / 12, h = bh - b * 12;
  const int tid = threadIdx.x, lane = tid & 63, w = tid >> 6;
  const int quad = lane >> 4, l16 = lane & 15;
  const int q0 = qx * 128 + w * 32;

  __shared__ __align__(16) __bf16 Ks[2][64 * 64];     // [buf][key][d-swz]
  __shared__ __align__(16) __bf16 Vs[2][64 * 64];     // [buf][d][key-swz]

  const __bf16* Qbase = Qh + (size_t)bh * 2048 * 64;
  const __bf16* Kbase = Kh + (size_t)bh * 2048 * 64;
  const __bf16* Vbase = Vt + (size_t)bh * 64 * 2048;
  const float* biasB = biasF + b * 2048;

  // Q B-frags (plain layout, pre-scaled): B[k=d][n=q] from Qh[q][d]
  bf16x8 bqf[2][2];
#pragma unroll
  for (int qt = 0; qt < 2; ++qt)
#pragma unroll
    for (int c = 0; c < 2; ++c)
      bqf[qt][c] =
          *(const bf16x8*)&Qbase[(size_t)(q0 + qt * 16 + l16) * 64 + c * 32 + quad * 8];

  // staging (128 B rows): chunk c covers rows c*8 + (lane>>3), col (lane&7)*8
  const int r0 = (w * 2) * 8 + (lane >> 3);
  const int r1 = (w * 2 + 1) * 8 + (lane >> 3);
  const int scol = (lane & 7) * 8;
  const int d0 = (w * 2) * 512;
  const int d1 = (w * 2 + 1) * 512;
  const int col0 = (quad ^ (l16 & 7)) * 8;

  // prologue: stage tile 0 into buffer 0
  glds16(&Kbase[(size_t)r0 * 64 + scol], &Ks[0][d0]);
  glds16(&Kbase[(size_t)r1 * 64 + scol], &Ks[0][d1]);
  glds16(&Vbase[(size_t)r0 * 2048 + scol], &Vs[0][d0]);
  glds16(&Vbase[(size_t)r1 * 2048 + scol], &Vs[0][d1]);

  floatx4 o[4][2] = {};   // O^T accs: [d-tile][q-tile]
  floatx4 os[2] = {};     // rS accs via ones-MFMA
  bf16x8 ones8;
#pragma unroll
  for (int j = 0; j < 8; ++j) ones8[j] = (__bf16)1.0f;

  for (int it = 0; it < 32; ++it) {
    const int kt = it * 64;
    const int cur = it & 1;
    const int nxt = cur ^ 1;
    const int nkt = (kt + 64) & 2047;  // wrap: last-iter prefetch is harmless

    __syncthreads();  // drains tile-`it` staging (in flight since iter it-1)

    // ---- prefetch tile it+1 into the other buffer (overlaps compute below)
    glds16(&Kbase[(size_t)(nkt + r0) * 64 + scol], &Ks[nxt][d0]);
    glds16(&Kbase[(size_t)(nkt + r1) * 64 + scol], &Ks[nxt][d1]);
    glds16(&Vbase[(size_t)r0 * 2048 + nkt + scol], &Vs[nxt][d0]);
    glds16(&Vbase[(size_t)r1 * 2048 + nkt + scol], &Vs[nxt][d1]);

    // ---- scores S^T with bias in acc-init: 4 key-tiles x 2 q-tiles
    floatx4 sc[4][2];
#pragma unroll
    for (int t = 0; t < 4; ++t) {
      const float4 bf4 = *(const float4*)&biasB[kt + t * 16 + quad * 4];
      bf16x8 ak0 = *(const bf16x8*)&Ks[cur][(t * 16 + l16) * 64 + col0];
      bf16x8 ak1 = *(const bf16x8*)&Ks[cur][(t * 16 + l16) * 64 + (col0 ^ 32)];
#pragma unroll
      for (int qt = 0; qt < 2; ++qt) {
        floatx4 zz;
        zz[0] = bf4.x; zz[1] = bf4.y; zz[2] = bf4.z; zz[3] = bf4.w;
        zz = MFMA_BF16(ak0, bqf[qt][0], zz);
        zz = MFMA_BF16(ak1, bqf[qt][1], zz);
        sc[t][qt] = zz;
      }
    }
    // ---- p = exp2(s); pack pairs to bf16 words (keys +0,1 / +2,3 per word)
    unsigned int u[4][2][2];
#pragma unroll
    for (int t = 0; t < 4; ++t)
#pragma unroll
      for (int qt = 0; qt < 2; ++qt) {
        const float e0 = __builtin_amdgcn_exp2f(sc[t][qt][0]);
        const float e1 = __builtin_amdgcn_exp2f(sc[t][qt][1]);
        const float e2 = __builtin_amdgcn_exp2f(sc[t][qt][2]);
        const float e3 = __builtin_amdgcn_exp2f(sc[t][qt][3]);
        asm("v_cvt_pk_bf16_f32 %0, %1, %2" : "=v"(u[t][qt][0]) : "v"(e0), "v"(e1));
        asm("v_cvt_pk_bf16_f32 %0, %1, %2" : "=v"(u[t][qt][1]) : "v"(e2), "v"(e3));
      }
    // ---- in-register P^T -> B-frags; O^T += V^T @ P^T; rS += ones @ P^T
#pragma unroll
    for (int c = 0; c < 2; ++c) {
      bf16x8 bp[2];
#pragma unroll
      for (int qt = 0; qt < 2; ++qt) {
        unsigned int w0 = u[2 * c][qt][0], w1 = u[2 * c][qt][1];
        unsigned int w2 = u[2 * c + 1][qt][0], w3 = u[2 * c + 1][qt][1];
        perm32_swap(w0, w2);
        perm32_swap(w1, w3);
        perm16_swap(w0, w2);
        perm16_swap(w1, w3);
        union { unsigned int wd[4]; bf16x8 v; } ub;
        ub.wd[0] = w0; ub.wd[1] = w1; ub.wd[2] = w2; ub.wd[3] = w3;
        bp[qt] = ub.v;
        os[qt] = MFMA_BF16(ones8, bp[qt], os[qt]);
      }
#pragma unroll
      for (int dt = 0; dt < 4; ++dt) {
        bf16x8 av = *(const bf16x8*)&Vs[cur][(dt * 16 + l16) * 64 + (col0 ^ (c * 32))];
#pragma unroll
        for (int qt = 0; qt < 2; ++qt) o[dt][qt] = MFMA_BF16(av, bp[qt], o[dt][qt]);
      }
    }
  }

  // ---- normalize + write ctx (every lane holds its q's sum in os[qt][0])
  float inv[2];
  inv[0] = 1.0f / os[0][0];
  inv[1] = 1.0f / os[1][0];
#pragma unroll
  for (int dt = 0; dt < 4; ++dt)
#pragma unroll
    for (int qt = 0; qt < 2; ++qt) {
      const int q = q0 + qt * 16 + l16;
      const int d = h * 64 + dt * 16 + quad * 4;
      bf16x4 pv;
      pv[0] = (__bf16)(o[dt][qt][0] * inv[qt]);
      pv[1] = (__bf16)(o[dt][qt][1] * inv[qt]);
      pv[2] = (__bf16)(o[dt][qt][2] * inv[qt]);
      pv[3] = (__bf16)(o[dt][qt][3] * inv[qt]);
      *(bf16x4*)&ctx[(size_t)(b * 2048 + q) * 768 + d] = pv;
    }
}

// ---------------------------------------------------------------------------
extern "C" void kernel_launch(void* const* d_in, const int* in_sizes, int n_in,
                              void* d_out, int out_size, void* d_ws, size_t ws_size,
                              hipStream_t stream) {
  const float* q = (const float*)d_in[0];
  const float* k = (const float*)d_in[1];
  const float* v = (const float*)d_in[2];
  const int* mask = (const int*)d_in[3];
  const float* Wq = (const float*)d_in[4];
  const float* bq = (const float*)d_in[5];
  const float* Wk = (const float*)d_in[6];
  const float* bk = (const float*)d_in[7];
  const float* Wv = (const float*)d_in[8];
  const float* bv = (const float*)d_in[9];
  const float* Wo = (const float*)d_in[10];
  const float* bo = (const float*)d_in[11];
  float* out = (float*)d_out;

  char* ws = (char*)d_ws;
  const size_t SZ = (size_t)8192 * 768 * 2;   // 12.58 MB
  const size_t WSZ = (size_t)768 * 768 * 2;   // 1.18 MB
  __bf16* Qh = (__bf16*)(ws);
  __bf16* Kh = (__bf16*)(ws + SZ);
  __bf16* Vt = (__bf16*)(ws + 2 * SZ);
  __bf16* ctx = (__bf16*)(ws + 3 * SZ);
  __bf16* Wtq = (__bf16*)(ws + 4 * SZ);
  __bf16* Wtk = (__bf16*)(ws + 4 * SZ + WSZ);
  __bf16* Wtv = (__bf16*)(ws + 4 * SZ + 2 * WSZ);
  __bf16* Wto = (__bf16*)(ws + 4 * SZ + 3 * WSZ);
  float* biasF = (float*)(ws + 4 * SZ + 4 * WSZ);  // 4*2048 f32 = 32 KB

  prep_transpose<<<dim3(24, 24, 4), 256, 0, stream>>>(Wq, Wk, Wv, Wo, Wtq, Wtk,
                                                      Wtv, Wto, mask, biasF);
  qkv_gemm<<<dim3(6, 64, 3), 256, 0, stream>>>(Wtq, Wtk, Wtv, q, k, v, bq, bk, bv,
                                               Qh, Kh, Vt);
  attn_kernel<<<dim3(16, 48), 256, 0, stream>>>(Qh, Kh, Vt, biasF, ctx);
  out_gemm<<<dim3(6, 64), 256, 0, stream>>>(Wto, ctx, bo, out);
}